// Round 6
// baseline (330.848 us; speedup 1.0000x reference)
//
#include <hip/hip_runtime.h>

typedef unsigned short u16;
typedef unsigned int   u32;

typedef __bf16 bf16x8 __attribute__((ext_vector_type(8)));
typedef float  f32x4  __attribute__((ext_vector_type(4)));

__device__ __forceinline__ float bf2f(u16 u){ u32 x = ((u32)u) << 16; return __builtin_bit_cast(float, x); }
__device__ __forceinline__ u16 f2bf(float f){
  u32 u = __builtin_bit_cast(u32, f);
  u32 r = (u + 0x7FFFu + ((u >> 16) & 1u)) >> 16;
  return (u16)r;
}
// pack bf16(a) low16, bf16(b) high16
__device__ __forceinline__ u32 pk2bf(float a, float b){
  u32 ua = __builtin_bit_cast(u32, a) + 0x8000u;
  u32 ub = __builtin_bit_cast(u32, b) + 0x8000u;
  return __builtin_amdgcn_perm(ub, ua, 0x07060302u);
}
// async global->LDS, 16B/lane; lds base wave-uniform, dest = base + lane*16
__device__ __forceinline__ void glds16(const void* g, void* l){
  __builtin_amdgcn_global_load_lds((const __attribute__((address_space(1))) void*)g,
                                   (__attribute__((address_space(3))) void*)l, 16, 0, 0);
}

// ---------------- 64x64 transpose+cast tile: dst[c][r] = bf16(src[r][c]) ----------------
__device__ __forceinline__ void ttile64(const float* __restrict__ src, u16* __restrict__ dst,
                                        int R, int C, int bx, int by, u16* T){
  int c0 = bx * 64, r0 = by * 64;
  int tr  = threadIdx.x >> 3;           // 0..31
  int tc8 = (threadIdx.x & 7) * 8;
  #pragma unroll
  for (int it = 0; it < 2; ++it){
    int rr = tr + it * 32;
    const float* sp = src + (size_t)(r0 + rr) * C + c0 + tc8;
    float4 f0 = *(const float4*)sp, f1 = *(const float4*)(sp + 4);
    u16 v[8] = { f2bf(f0.x), f2bf(f0.y), f2bf(f0.z), f2bf(f0.w),
                 f2bf(f1.x), f2bf(f1.y), f2bf(f1.z), f2bf(f1.w) };
    #pragma unroll
    for (int j = 0; j < 8; ++j) T[(tc8 + j) * 72 + rr] = v[j];
  }
  __syncthreads();
  int tcw = threadIdx.x >> 3;
  int tr8 = (threadIdx.x & 7) * 8;
  #pragma unroll
  for (int it = 0; it < 2; ++it){
    int cc = tcw + it * 32;
    *(uint4*)(dst + (size_t)(c0 + cc) * R + r0 + tr8) = *(const uint4*)&T[cc * 72 + tr8];
  }
}

// ---------------- fused preprocessing: wq^T, wk^T, wp^T, cvt(qr) ----------------
// blocks [0,3072) wqT | [3072,3296) wkT | [3296,3408) wpT | [3408,4944) cvt qr
__global__ __launch_bounds__(256) void prep(const float* __restrict__ wq,
    const float* __restrict__ wk, const float* __restrict__ wp,
    const float* __restrict__ qr, u16* __restrict__ wqT,
    u16* __restrict__ wkwpT, u16* __restrict__ qrb, int do_cvt){
  __shared__ u16 T[64 * 72];
  int id = blockIdx.x;
  if (id < 3072) {
    ttile64(wq, wqT, 1536, 8192, id & 127, id >> 7, T);
  } else if (id < 3296) {
    int r = id - 3072;
    ttile64(wk, wkwpT, 7168, 128, r & 1, r >> 1, T);
  } else if (id < 3408) {
    int r = id - 3296;
    ttile64(wp, wkwpT + (size_t)128 * 7168, 7168, 64, 0, r, T);
  } else if (do_cvt) {
    int r = id - 3408;
    size_t i = ((size_t)r * 256 + threadIdx.x) * 8;
    const float4* a4 = (const float4*)(qr + i);
    float4 f0 = a4[0], f1 = a4[1];
    u32 w[4] = { pk2bf(f0.x, f0.y), pk2bf(f0.z, f0.w), pk2bf(f1.x, f1.y), pk2bf(f1.z, f1.w) };
    *(uint4*)(qrb + i) = *(const uint4*)w;
  }
}

// ---------------- split-K projection: atomically accumulate into P2[2048][192] f32 ----------------
__global__ __launch_bounds__(256) void proj_splitk(const float* __restrict__ X,
    const u16* __restrict__ BT, float* __restrict__ P2){
  constexpr int Kf = 7168;
  const int s = blockIdx.x, m0 = blockIdx.y * 64;
  const int kbase = s * 448;
  __shared__ u16 As[2 * 64 * 36];      // [kc][64][36] padded (VALU-packed stores)
  __shared__ u16 Bs[2 * 192 * 32];     // [kc][192][32] unpadded (glds)
  const int tid = threadIdx.x, wave = tid >> 6, lane = tid & 63;
  const int row = lane & 15, quad = lane >> 4;
  const int wm = (wave & 1) * 32, wn = (wave >> 1) * 96;

  const f32x4 zero = {0.f, 0.f, 0.f, 0.f};
  f32x4 acc[2][6];
  #pragma unroll
  for (int mt = 0; mt < 2; ++mt)
    #pragma unroll
    for (int nt = 0; nt < 6; ++nt) acc[mt][nt] = zero;

  for (int kb = 0; kb < 7; ++kb) {
    int k0 = kbase + kb * 64;
    #pragma unroll
    for (int c = 0; c < 6; ++c) {
      int chunk = wave * 6 + c;
      int kc = chunk / 12, rem = chunk % 12;
      int r = rem * 16 + (lane >> 2), col = (lane & 3) * 8;
      glds16(BT + (size_t)r * Kf + k0 + kc * 32 + col, (void*)&Bs[chunk * 512]);
    }
    #pragma unroll
    for (int c = 0; c < 2; ++c) {
      int idx = tid + c * 256;
      int r = idx >> 3, kf = (idx & 7) * 8;
      const float4* ap = (const float4*)(X + (size_t)(m0 + r) * Kf + k0 + kf);
      float4 f0 = ap[0], f1 = ap[1];
      u32 w[4] = { pk2bf(f0.x, f0.y), pk2bf(f0.z, f0.w), pk2bf(f1.x, f1.y), pk2bf(f1.z, f1.w) };
      *(uint4*)&As[(kf >> 5) * 2304 + r * 36 + (kf & 31)] = *(const uint4*)w;
    }
    __syncthreads();
    #pragma unroll
    for (int ks = 0; ks < 2; ++ks) {
      bf16x8 af[2], bfr[6];
      #pragma unroll
      for (int mt = 0; mt < 2; ++mt) af[mt] = *(const bf16x8*)&As[ks * 2304 + (wm + mt * 16 + row) * 36 + quad * 8];
      #pragma unroll
      for (int nt = 0; nt < 6; ++nt) bfr[nt] = *(const bf16x8*)&Bs[ks * 6144 + (wn + nt * 16 + row) * 32 + quad * 8];
      #pragma unroll
      for (int mt = 0; mt < 2; ++mt)
        #pragma unroll
        for (int nt = 0; nt < 6; ++nt)
          acc[mt][nt] = __builtin_amdgcn_mfma_f32_16x16x32_bf16(af[mt], bfr[nt], acc[mt][nt], 0, 0, 0);
    }
    __syncthreads();
  }
  #pragma unroll
  for (int mt = 0; mt < 2; ++mt)
    #pragma unroll
    for (int nt = 0; nt < 6; ++nt)
      #pragma unroll
      for (int r = 0; r < 4; ++r) {
        int rr = m0 + wm + mt * 16 + quad * 4 + r;
        int cc = wn + nt * 16 + row;
        unsafeAtomicAdd(&P2[(size_t)rr * 192 + cc], acc[mt][nt][r]);
      }
}

// ---------------- LayerNorm + RoPE from P2 -> Kbf (bf16), WT (f32, [h][tok]) ----------------
__global__ __launch_bounds__(64) void reduce_lnrope(const float* __restrict__ P2,
    const float* __restrict__ cosb, const float* __restrict__ sinb,
    const float* __restrict__ gam, const float* __restrict__ bet,
    u16* __restrict__ Kout, float* __restrict__ WoutT){
  int tok = blockIdx.x, lane = threadIdx.x;
  const float* p = P2 + (size_t)tok * 192;
  float v0 = p[2 * lane], v1 = p[2 * lane + 1], w = p[128 + lane];
  WoutT[(size_t)lane * 2048 + tok] = w;     // transposed: [h][tok]
  float sm = v0 + v1;
  #pragma unroll
  for (int m = 1; m < 64; m <<= 1) sm += __shfl_xor(sm, m);
  float mu = sm * (1.f / 128.f);
  float d0 = v0 - mu, d1 = v1 - mu;
  float sq = d0 * d0 + d1 * d1;
  #pragma unroll
  for (int m = 1; m < 64; m <<= 1) sq += __shfl_xor(sq, m);
  float rs = rsqrtf(sq * (1.f / 128.f) + 1e-6f);
  float kn0 = d0 * rs * gam[2 * lane]     + bet[2 * lane];
  float kn1 = d1 * rs * gam[2 * lane + 1] + bet[2 * lane + 1];
  float o0 = kn0, o1 = kn1;
  if (lane < 32) {
    float c  = cosb[tok * 64 + 2 * lane];
    float sn = sinb[tok * 64 + 2 * lane];
    o0 = kn0 * c - kn1 * sn;
    o1 = kn1 * c + kn0 * sn;
  }
  Kout[tok * 128 + 2 * lane]     = f2bf(o0);
  Kout[tok * 128 + 2 * lane + 1] = f2bf(o1);
}

// ---------------- Q-GEMM (M=2048,N=8192,K=1536), BK=64, fused RoPE epilogue (control) ----------------
template<bool AGLDS>
__global__ __launch_bounds__(256) void qgemm(const void* __restrict__ Aptr,
    const u16* __restrict__ BT, const float* __restrict__ cosb,
    const float* __restrict__ sinb, u16* __restrict__ Qout){
  constexpr int K = 1536, N = 8192;
  __shared__ u16 As[2 * 128 * 32];   // [kc][128][32] unpadded (glds / packed stores)
  __shared__ u16 Bs[2 * 128 * 32];
  const int tid = threadIdx.x, wave = tid >> 6, lane = tid & 63;
  const int row = lane & 15, quad = lane >> 4;
  const int wm = (wave >> 1) * 64, wn = (wave & 1) * 64;
  const int m0 = blockIdx.y * 128, n0 = blockIdx.x * 128;

  const f32x4 zero = {0.f, 0.f, 0.f, 0.f};
  f32x4 acc[4][4];
  #pragma unroll
  for (int mt = 0; mt < 4; ++mt)
    #pragma unroll
    for (int nt = 0; nt < 4; ++nt) acc[mt][nt] = zero;

  for (int k0 = 0; k0 < K; k0 += 64) {
    #pragma unroll
    for (int c = 0; c < 4; ++c) {            // B: 16 chunks (1024B), 4/wave
      int chunk = wave * 4 + c;
      int kc = chunk >> 3, rg = chunk & 7;
      int r = rg * 16 + (lane >> 2), col = kc * 32 + (lane & 3) * 8;
      glds16(BT + (size_t)(n0 + r) * K + k0 + col, (void*)&Bs[chunk * 512]);
    }
    if (AGLDS) {
      #pragma unroll
      for (int c = 0; c < 4; ++c) {
        int chunk = wave * 4 + c;
        int kc = chunk >> 3, rg = chunk & 7;
        int r = rg * 16 + (lane >> 2), col = kc * 32 + (lane & 3) * 8;
        glds16((const u16*)Aptr + (size_t)(m0 + r) * K + k0 + col, (void*)&As[chunk * 512]);
      }
    } else {
      #pragma unroll
      for (int c = 0; c < 4; ++c) {          // A: f32 load + pack, 128x64
        int idx = tid + c * 256;
        int r = idx >> 3, kf = (idx & 7) * 8;
        const float4* ap = (const float4*)((const float*)Aptr + (size_t)(m0 + r) * K + k0 + kf);
        float4 f0 = ap[0], f1 = ap[1];
        u32 w[4] = { pk2bf(f0.x, f0.y), pk2bf(f0.z, f0.w), pk2bf(f1.x, f1.y), pk2bf(f1.z, f1.w) };
        *(uint4*)&As[(kf >> 5) * 4096 + r * 32 + (kf & 31)] = *(const uint4*)w;
      }
    }
    __syncthreads();
    #pragma unroll
    for (int kk = 0; kk < 2; ++kk) {
      bf16x8 af[4], bfr[4];
      #pragma unroll
      for (int mt = 0; mt < 4; ++mt) af[mt]  = *(const bf16x8*)&As[kk * 4096 + (wm + mt * 16 + row) * 32 + quad * 8];
      #pragma unroll
      for (int nt = 0; nt < 4; ++nt) bfr[nt] = *(const bf16x8*)&Bs[kk * 4096 + (wn + nt * 16 + row) * 32 + quad * 8];
      #pragma unroll
      for (int mt = 0; mt < 4; ++mt)
        #pragma unroll
        for (int nt = 0; nt < 4; ++nt)
          acc[mt][nt] = __builtin_amdgcn_mfma_f32_16x16x32_bf16(af[mt], bfr[nt], acc[mt][nt], 0, 0, 0);
    }
    __syncthreads();
  }

  const bool roped = (wn == 0);
  #pragma unroll
  for (int mt = 0; mt < 4; ++mt)
    #pragma unroll
    for (int nt = 0; nt < 4; ++nt)
      #pragma unroll
      for (int r = 0; r < 4; ++r) {
        int rr = m0 + wm + mt * 16 + quad * 4 + r;
        int cc = n0 + wn + nt * 16 + row;
        float v = acc[mt][nt][r];
        float o = v;
        if (roped) {
          int hd = (wn + nt * 16 + row) & 127;
          float c = cosb[rr * 64 + hd];
          float s = sinb[rr * 64 + hd];
          float vo = __shfl_xor(v, 1);
          o = (cc & 1) ? (v * c + vo * s) : (v * c - vo * s);
        }
        Qout[(size_t)rr * N + cc] = f2bf(o);
      }
}

// ---------------- fused scores: distinct A/B LDS buffers, 2-pair unrolled pipeline ----------------
__global__ __launch_bounds__(256) void attn_kernel(const u16* __restrict__ Q,
    const u16* __restrict__ Kb, const float* __restrict__ WT, float* __restrict__ out){
  int blk = blockIdx.x;                       // 512 blocks
  int x = blk & 7, kt = (blk >> 3) & 7, hs = (blk >> 6) & 1, g4 = (blk >> 7) & 3;
  int p = x + 8 * g4;                         // 0..31
  int b = p >> 4, qt = p & 15;
  int q0 = qt * 64, k0 = kt * 128;

  const int tid = threadIdx.x, wave = tid >> 6, lane = tid & 63;
  const int row = lane & 15, quad = lane >> 4;
  const int wm = (wave >> 1) * 32;            // q offset (0/32)
  const int wn = (wave & 1) * 64;             // k offset (0/64)

  __shared__ u16 ShA[16384];                  // 32 KB (also holds K tile initially)
  __shared__ u16 ShB[16384];                  // 32 KB
  __shared__ float Ws[32 * 64];               // 8 KB: [h_local][q_local]

  // stage K tile 128x128 into ShA as [r][128]
  #pragma unroll
  for (int c = 0; c < 8; ++c) {
    int g = wave * 8 + c;
    int rr = g * 4 + (lane >> 4), col = (lane & 15) * 8;
    glds16(Kb + (size_t)(b * 1024 + k0 + rr) * 128 + col, (void*)&ShA[g * 512]);
  }
  {
    int hl = tid >> 3, qq = (tid & 7) * 8;
    const float* srcw = WT + (size_t)(hs * 32 + hl) * 2048 + b * 1024 + q0 + qq;
    *(float4*)&Ws[hl * 64 + qq]     = *(const float4*)srcw;
    *(float4*)&Ws[hl * 64 + qq + 4] = *(const float4*)(srcw + 4);
  }
  __syncthreads();

  bf16x8 bfr[4][4];                           // h-invariant K fragments (read once)
  #pragma unroll
  for (int ks = 0; ks < 4; ++ks)
    #pragma unroll
    for (int nt = 0; nt < 4; ++nt)
      bfr[ks][nt] = *(const bf16x8*)&ShA[(wn + nt * 16 + row) * 128 + ks * 32 + quad * 8];
  __syncthreads();                            // K reads done before Q overwrites ShA

  const u16* Qbase = Q + (size_t)(b * 1024 + q0) * 8192;
  auto stage = [&](u16* buf, int pairIdx){    // 2 heads (32 KB): 32 chunks, 8/wave
    int h0 = hs * 32 + pairIdx * 2;
    #pragma unroll
    for (int c = 0; c < 8; ++c) {
      int g = wave * 8 + c;
      int hsub = g >> 4, rem = g & 15;
      int kc = rem >> 2, rg = rem & 3;
      glds16(Qbase + (size_t)(rg * 16 + (lane >> 2)) * 8192 + (h0 + hsub) * 128 + kc * 32 + (lane & 3) * 8,
             (void*)&buf[hsub * 8192 + rem * 512]);
    }
  };

  const f32x4 zero = {0.f, 0.f, 0.f, 0.f};
  f32x4 sacc[2][4];
  #pragma unroll
  for (int mt = 0; mt < 2; ++mt)
    #pragma unroll
    for (int nt = 0; nt < 4; ++nt) sacc[mt][nt] = zero;

  auto compute = [&](const u16* S, int pairIdx){
    #pragma unroll
    for (int hsub = 0; hsub < 2; ++hsub) {
      f32x4 lg[2][4];
      #pragma unroll
      for (int mt = 0; mt < 2; ++mt)
        #pragma unroll
        for (int nt = 0; nt < 4; ++nt) lg[mt][nt] = zero;
      #pragma unroll
      for (int ks = 0; ks < 4; ++ks) {
        bf16x8 af0 = *(const bf16x8*)&S[hsub * 8192 + ks * 2048 + (wm +      row) * 32 + quad * 8];
        bf16x8 af1 = *(const bf16x8*)&S[hsub * 8192 + ks * 2048 + (wm + 16 + row) * 32 + quad * 8];
        #pragma unroll
        for (int nt = 0; nt < 4; ++nt) {
          lg[0][nt] = __builtin_amdgcn_mfma_f32_16x16x32_bf16(af0, bfr[ks][nt], lg[0][nt], 0, 0, 0);
          lg[1][nt] = __builtin_amdgcn_mfma_f32_16x16x32_bf16(af1, bfr[ks][nt], lg[1][nt], 0, 0, 0);
        }
      }
      int hl = pairIdx * 2 + hsub;
      f32x4 w0 = *(const f32x4*)&Ws[hl * 64 + wm +      quad * 4];
      f32x4 w1 = *(const f32x4*)&Ws[hl * 64 + wm + 16 + quad * 4];
      #pragma unroll
      for (int nt = 0; nt < 4; ++nt)
        #pragma unroll
        for (int r = 0; r < 4; ++r) {
          sacc[0][nt][r] += w0[r] * fmaxf(lg[0][nt][r], 0.f);
          sacc[1][nt][r] += w1[r] * fmaxf(lg[1][nt][r], 0.f);
        }
    }
  };

  stage(ShA, 0);                              // prefetch pair 0
  for (int hp = 0; hp < 16; hp += 2) {
    __syncthreads();                          // pair hp (ShA) landed
    stage(ShB, hp + 1);                       // prefetch next pair into the OTHER buffer
    compute(ShA, hp);
    __syncthreads();                          // pair hp+1 (ShB) landed
    if (hp + 2 < 16) stage(ShA, hp + 2);
    compute(ShB, hp + 1);
  }

  const float scale = 0.088388347648318447f;  // 128^-0.5
  #pragma unroll
  for (int mt = 0; mt < 2; ++mt)
    #pragma unroll
    for (int nt = 0; nt < 4; ++nt)
      #pragma unroll
      for (int r = 0; r < 4; ++r) {
        int qq = q0 + wm + mt * 16 + quad * 4 + r;
        int kk = k0 + wn + nt * 16 + row;
        unsafeAtomicAdd(&out[((size_t)b << 20) + (size_t)qq * 1024 + kk], scale * sacc[mt][nt][r]);
      }
}

extern "C" void kernel_launch(void* const* d_in, const int* in_sizes, int n_in,
                              void* d_out, int out_size, void* d_ws, size_t ws_size,
                              hipStream_t stream) {
  const float* x    = (const float*)d_in[0];   // [2048][7168]
  const float* qr   = (const float*)d_in[1];   // [2048][1536]
  const float* cosb = (const float*)d_in[2];   // [2048][64]
  const float* sinb = (const float*)d_in[3];   // [2048][64]
  const float* wq   = (const float*)d_in[4];   // [1536][8192]
  const float* wk   = (const float*)d_in[5];   // [7168][128]
  const float* wp   = (const float*)d_in[6];   // [7168][64]
  const float* gam  = (const float*)d_in[7];   // [128]
  const float* bet  = (const float*)d_in[8];   // [128]
  float* out = (float*)d_out;                  // [2][1024][1024] f32

  char* ws = (char*)d_ws;
  u16*   wqT  = (u16*)(ws + 0);            // [8192][1536] bf16 = 25,165,824 B
  u16*   wkwpT= (u16*)(ws + 25165824);     // [192][7168] bf16 = 2,752,512 B
  float* WT   = (float*)(ws + 27918336);   // [64][2048] f32 = 524,288 B
  u16*   Kbf  = (u16*)(ws + 28442624);     // [2048][128] bf16 = 524,288 B
  u16*   Qbf  = (u16*)(ws + 28966912);     // [2048][8192] bf16 = 33,554,432 B -> 62,521,344
  float* P2   = (float*)(ws + 28966912);   // [2048][192] f32 = 1,572,864 B — ALIASES Qbf head
                                           // (P2 dead before qgemm writes Qbf: proj->reduce->qgemm order)
  const size_t QRB_OFF = 62521344;
  u16*   qrb  = (u16*)(ws + QRB_OFF);      // [2048][1536] bf16 = 6,291,456 B -> 68,812,800
  const bool big_ws = (ws_size >= (size_t)68812800);

  (void)in_sizes; (void)n_in;

  hipMemsetAsync(d_out, 0, (size_t)out_size * 4, stream);
  hipMemsetAsync(P2, 0, (size_t)2048 * 192 * 4, stream);

  prep<<<4944, 256, 0, stream>>>(wq, wk, wp, qr, wqT, wkwpT, qrb, big_ws ? 1 : 0);

  proj_splitk<<<dim3(16, 32), 256, 0, stream>>>(x, wkwpT, P2);
  reduce_lnrope<<<2048, 64, 0, stream>>>(P2, cosb, sinb, gam, bet, Kbf, WT);

  if (big_ws) {
    qgemm<true><<<dim3(64, 16), 256, 0, stream>>>(qrb, wqT, cosb, sinb, Qbf);
  } else {
    qgemm<false><<<dim3(64, 16), 256, 0, stream>>>(qr, wqT, cosb, sinb, Qbf);
  }

  attn_kernel<<<512, 256, 0, stream>>>(Qbf, Kbf, WT, out);
}